// Round 9
// baseline (109.164 us; speedup 1.0000x reference)
//
#include <hip/hip_runtime.h>
#include <hip/hip_bf16.h>

typedef __bf16 bf16x8 __attribute__((ext_vector_type(8)));
typedef unsigned short u16x8 __attribute__((ext_vector_type(8)));
typedef unsigned int u32x4 __attribute__((ext_vector_type(4)));
typedef float f32x4 __attribute__((ext_vector_type(4)));

#define SLEN 2048
#define DDIM 128
#define NH   32
#define NKVH 8
#define KVB  32
#define KPAD 136
#define VPAD 40
#define PW2  20
#define MINIT  -1e30f
#define MASKED -3e30f

static __device__ __forceinline__ unsigned short f2bfu(float f) {
  union { float f; unsigned u; } x; x.f = f;
  return (unsigned short)((x.u + 0x7fffu + ((x.u >> 16) & 1u)) >> 16);
}
static __device__ __forceinline__ float bfu2f(unsigned short u) {
  union { unsigned u; float f; } x; x.u = ((unsigned)u) << 16;
  return x.f;
}
static __device__ __forceinline__ unsigned cvt_pk_bf16(float lo, float hi) {
  unsigned r;
  asm("v_cvt_pk_bf16_f32 %0, %1, %2" : "=v"(r) : "v"(lo), "v"(hi));
  return r;
}
static __device__ __forceinline__ f32x4 mfma_bf16(u16x8 a, u16x8 b, f32x4 c) {
  return __builtin_amdgcn_mfma_f32_16x16x32_bf16(
      __builtin_bit_cast(bf16x8, a), __builtin_bit_cast(bf16x8, b), c, 0, 0, 0);
}

// ---- fused prepass: K -> bf16 (blocks 0..1023), V -> bf16 transposed (1024..3071) ----
__global__ __launch_bounds__(256) void conv_kv(const float* __restrict__ k,
                                               const float* __restrict__ v,
                                               unsigned* __restrict__ kdst,
                                               unsigned short* __restrict__ vt) {
  __shared__ unsigned T32[32][17];
  const int bb = blockIdx.x;
  if (bb < 1024) {
    const int i = bb * 256 + threadIdx.x;
    const float4 f0 = ((const float4*)k)[2 * i];
    const float4 f1 = ((const float4*)k)[2 * i + 1];
    u32x4 o = { cvt_pk_bf16(f0.x, f0.y), cvt_pk_bf16(f0.z, f0.w),
                cvt_pk_bf16(f1.x, f1.y), cvt_pk_bf16(f1.z, f1.w) };
    ((u32x4*)kdst)[i] = o;
    return;
  }
  const int b   = bb - 1024;
  const int dt  = b & 3;
  const int st  = (b >> 2) & 63;
  const int kvh = b >> 8;
  const int r  = threadIdx.x >> 3;
  const int cg = threadIdx.x & 7;
  const float4 f = *(const float4*)(v + ((size_t)(kvh * SLEN + st * 32 + r) * DDIM) + dt * 32 + cg * 4);
  T32[r][cg * 2]     = cvt_pk_bf16(f.x, f.y);
  T32[r][cg * 2 + 1] = cvt_pk_bf16(f.z, f.w);
  __syncthreads();
  const int dr = threadIdx.x >> 3;
  const unsigned sel = (dr & 1) ? 0x07060302u : 0x05040100u;
  const unsigned a0 = T32[cg * 4 + 0][dr >> 1], a1 = T32[cg * 4 + 1][dr >> 1];
  const unsigned a2 = T32[cg * 4 + 2][dr >> 1], a3 = T32[cg * 4 + 3][dr >> 1];
  unsigned short* vp = vt + (size_t)kvh * DDIM * SLEN + (size_t)(dt * 32 + dr) * SLEN + st * 32 + cg * 4;
  const unsigned w0 = __builtin_amdgcn_perm(a1, a0, sel);
  const unsigned w1 = __builtin_amdgcn_perm(a3, a2, sel);
  vp[0] = (unsigned short)(w0 & 0xffff);
  vp[1] = (unsigned short)(w0 >> 16);
  vp[2] = (unsigned short)(w1 & 0xffff);
  vp[3] = (unsigned short)(w1 >> 16);
}

// ---- attention chunk kernel: NG q-groups of 16 rows per wave ----
template <int NG, int NCH>
__global__ __launch_bounds__(256, NG == 1 ? 4 : 3) void attn_fwd(
    const float* __restrict__ q, const unsigned short* __restrict__ kbf,
    const unsigned short* __restrict__ vtg, const float* __restrict__ sinks,
    const int* __restrict__ bwp, float* __restrict__ out,
    unsigned short* __restrict__ pO, float* __restrict__ pm,
    float* __restrict__ pl) {
  constexpr int QBLK = 64 * NG;
  constexpr int NQT  = SLEN / QBLK;
  __shared__ unsigned short Kl[KVB][KPAD];
  __shared__ unsigned short Vt[DDIM][VPAD];
  __shared__ unsigned Pex[4][16][PW2];    // time-shared across groups
  __shared__ float SmS[4][NG][16];

  const int tid  = threadIdx.x;
  const int wid  = tid >> 6;
  const int lane = tid & 63;
  const int ln   = lane & 15;
  const int hi   = lane >> 4;

  const int B   = blockIdx.x;
  const int x   = B & 7;                  // XCD-resident kvh
  const int j   = B >> 3;
  constexpr int per = 4 * NCH;
  const int qt  = NQT - 1 - (j / per);    // descending: long chunks first
  const int rem = j % per;
  const int hh  = rem / NCH;
  const int c   = rem % NCH;
  const int h   = x * 4 + hh;
  const int kvh = x;
  const int q0  = qt * QBLK;
  const int qrow0 = q0 + wid * (16 * NG);

  const int bwv    = bwp[0];
  const int lo_off = (bwv > 0) ? (bwv - 1) : SLEN;

  const int T0 = max(0, q0 - lo_off) >> 5;
  const int T1 = (q0 + QBLK - 1) >> 5;
  const int N  = T1 - T0 + 1;
  const int ch = (N + NCH - 1) / NCH;
  const int Ts = T0 + c * ch;
  const int Te = min(T1, Ts + ch - 1);

  const float sm_scale = 0.08838834764831845f;

  // ---- Q fragments (MFMA B-operand after swap) ----
  u16x8 qf[NG][4];
  #pragma unroll
  for (int g = 0; g < NG; ++g) {
    const float* qp = q + ((size_t)(h * SLEN + qrow0 + g * 16 + ln) * DDIM) + hi * 8;
    #pragma unroll
    for (int dk = 0; dk < 4; ++dk) {
      float4 f0 = *(const float4*)(qp + dk * 32);
      float4 f1 = *(const float4*)(qp + dk * 32 + 4);
      u32x4 t = { cvt_pk_bf16(f0.x, f0.y), cvt_pk_bf16(f0.z, f0.w),
                  cvt_pk_bf16(f1.x, f1.y), cvt_pk_bf16(f1.z, f1.w) };
      qf[g][dk] = __builtin_bit_cast(u16x8, t);
    }
  }

  float m[NG], l[NG];
  f32x4 oacc[NG][8];
  #pragma unroll
  for (int g = 0; g < NG; ++g) {
    m[g] = MINIT; l[g] = 0.0f;
    #pragma unroll
    for (int nt = 0; nt < 8; ++nt) oacc[g][nt] = f32x4{0.f, 0.f, 0.f, 0.f};
  }

  const unsigned short* Kg = kbf + (size_t)kvh * SLEN * DDIM;
  const unsigned short* Vg = vtg + (size_t)kvh * DDIM * SLEN;

  const int kr0 = tid >> 4,          kc0 = (tid & 15) * 8;
  const int kr1 = (256 + tid) >> 4;
  const int vr0 = tid >> 2,          vc0 = (tid & 3) * 8;
  const int vr1 = (256 + tid) >> 2;

  if (Ts <= Te) {                         // non-empty chunk (block-uniform)
    const int kbS = Ts * 32, kbE = Te * 32;

    u16x8 pk0, pk1, pv0, pv1;
    {
      pk0 = *(const u16x8*)(Kg + (size_t)(kbS + kr0) * DDIM + kc0);
      pk1 = *(const u16x8*)(Kg + (size_t)(kbS + kr1) * DDIM + kc0);
      pv0 = *(const u16x8*)(Vg + (size_t)vr0 * SLEN + kbS + vc0);
      pv1 = *(const u16x8*)(Vg + (size_t)vr1 * SLEN + kbS + vc0);
    }

    for (int kb = kbS; kb <= kbE; kb += KVB) {
      __syncthreads();
      *(u16x8*)&Kl[kr0][kc0] = pk0;
      *(u16x8*)&Kl[kr1][kc0] = pk1;
      *(u16x8*)&Vt[vr0][vc0] = pv0;
      *(u16x8*)&Vt[vr1][vc0] = pv1;
      __syncthreads();

      {
        const int nb = min(kb + KVB, kbE);
        pk0 = *(const u16x8*)(Kg + (size_t)(nb + kr0) * DDIM + kc0);
        pk1 = *(const u16x8*)(Kg + (size_t)(nb + kr1) * DDIM + kc0);
        pv0 = *(const u16x8*)(Vg + (size_t)vr0 * SLEN + nb + vc0);
        pv1 = *(const u16x8*)(Vg + (size_t)vr1 * SLEN + nb + vc0);
      }

      if (kb > qrow0 + 16 * NG - 1) continue;         // above causal diag (wave)
      if (kb + KVB - 1 < qrow0 - lo_off) continue;    // before window (wave)

      // ---- QK^T swapped: each K-frag read feeds all NG groups ----
      f32x4 sA[NG], sB[NG];
      #pragma unroll
      for (int g = 0; g < NG; ++g) { sA[g] = f32x4{0,0,0,0}; sB[g] = f32x4{0,0,0,0}; }
      #pragma unroll
      for (int dk = 0; dk < 4; ++dk) {
        const u16x8 kf = *(const u16x8*)&Kl[ln][dk*32 + hi*8];
        #pragma unroll
        for (int g = 0; g < NG; ++g) sA[g] = mfma_bf16(kf, qf[g][dk], sA[g]);
      }
      #pragma unroll
      for (int dk = 0; dk < 4; ++dk) {
        const u16x8 kf = *(const u16x8*)&Kl[16 + ln][dk*32 + hi*8];
        #pragma unroll
        for (int g = 0; g < NG; ++g) sB[g] = mfma_bf16(kf, qf[g][dk], sB[g]);
      }

      // ---- mask + scale ----
      float p[NG][8];
      #pragma unroll
      for (int g = 0; g < NG; ++g) {
        const int qpos = qrow0 + g * 16 + ln;
        #pragma unroll
        for (int r = 0; r < 4; ++r) {
          const int kp0 = kb + hi * 4 + r;
          const int kp1 = kp0 + 16;
          p[g][r]     = ((kp0 <= qpos) && (kp0 >= qpos - lo_off)) ? sA[g][r] * sm_scale : MASKED;
          p[g][4 + r] = ((kp1 <= qpos) && (kp1 >= qpos - lo_off)) ? sB[g][r] * sm_scale : MASKED;
        }
      }

      // ---- row max per group ----
      float mx[NG];
      bool need = false;
      #pragma unroll
      for (int g = 0; g < NG; ++g) {
        float t = fmaxf(fmaxf(fmaxf(p[g][0], p[g][1]), fmaxf(p[g][2], p[g][3])),
                        fmaxf(fmaxf(p[g][4], p[g][5]), fmaxf(p[g][6], p[g][7])));
        t = fmaxf(t, __shfl_xor(t, 16));
        t = fmaxf(t, __shfl_xor(t, 32));
        mx[g] = t;
        need = need || (t > m[g] + 8.0f);
      }

      // ---- defer-max rescale (THR=8) ----
      if (__any(need)) {
        float corr[NG];
        #pragma unroll
        for (int g = 0; g < NG; ++g) {
          const float mn = fmaxf(m[g], mx[g]);
          corr[g] = __expf(m[g] - mn);
          l[g] *= corr[g];
          m[g] = mn;
          if (hi == 0) SmS[wid][g][ln] = corr[g];
        }
        #pragma unroll
        for (int g = 0; g < NG; ++g) {
          float c4[4];
          #pragma unroll
          for (int r = 0; r < 4; ++r) c4[r] = SmS[wid][g][hi * 4 + r];
          #pragma unroll
          for (int nt = 0; nt < 8; ++nt)
            #pragma unroll
            for (int r = 0; r < 4; ++r) oacc[g][nt][r] *= c4[r];
        }
      }

      // ---- exp + row sum ----
      #pragma unroll
      for (int g = 0; g < NG; ++g) {
        float s = 0.0f;
        #pragma unroll
        for (int jj = 0; jj < 8; ++jj) { p[g][jj] = __expf(p[g][jj] - m[g]); s += p[g][jj]; }
        s += __shfl_xor(s, 16);
        s += __shfl_xor(s, 32);
        l[g] += s;
      }

      // ---- pack P per group via time-shared slab, then shared-V PV ----
      u16x8 pa[NG];
      #pragma unroll
      for (int g = 0; g < NG; ++g) {
        Pex[wid][ln][hi * 2]         = cvt_pk_bf16(p[g][0], p[g][1]);
        Pex[wid][ln][hi * 2 + 1]     = cvt_pk_bf16(p[g][2], p[g][3]);
        Pex[wid][ln][8 + hi * 2]     = cvt_pk_bf16(p[g][4], p[g][5]);
        Pex[wid][ln][8 + hi * 2 + 1] = cvt_pk_bf16(p[g][6], p[g][7]);
        pa[g] = __builtin_bit_cast(u16x8, *(const u32x4*)&Pex[wid][ln][hi * 4]);
      }
      #pragma unroll
      for (int nt = 0; nt < 8; ++nt) {
        const u16x8 vb = *(const u16x8*)&Vt[nt*16 + ln][hi*8];
        #pragma unroll
        for (int g = 0; g < NG; ++g) oacc[g][nt] = mfma_bf16(pa[g], vb, oacc[g][nt]);
      }
    }
  }

  // ---- epilogue ----
  if (NCH == 1) {
    const float sink = sinks[h];
    #pragma unroll
    for (int g = 0; g < NG; ++g) {
      const float M  = fmaxf(m[g], sink);
      const float ed = __expf(m[g] - M);
      const float fac_ln = ed / (l[g] * ed + __expf(sink - M));
      if (hi == 0) SmS[wid][g][ln] = fac_ln;
      float fac4[4];
      #pragma unroll
      for (int r = 0; r < 4; ++r) fac4[r] = SmS[wid][g][hi * 4 + r];
      #pragma unroll
      for (int r = 0; r < 4; ++r) {
        float* op = out + ((size_t)(h * SLEN + qrow0 + g*16 + hi*4 + r) * DDIM) + ln;
        #pragma unroll
        for (int nt = 0; nt < 8; ++nt) op[nt * 16] = oacc[g][nt][r] * fac4[r];
      }
    }
  } else {
    const size_t Lb = ((size_t)(h * NQT + qt)) * NCH + c;
    #pragma unroll
    for (int g = 0; g < NG; ++g) {
      const int rbase = wid * (16 * NG) + g * 16;
      if (hi == 0) {
        pm[Lb * QBLK + rbase + ln] = m[g];
        pl[Lb * QBLK + rbase + ln] = l[g];
      }
      #pragma unroll
      for (int r = 0; r < 4; ++r) {
        unsigned short* po = pO + (Lb * QBLK + rbase + hi * 4 + r) * 128 + ln;
        #pragma unroll
        for (int nt = 0; nt < 8; ++nt) po[nt * 16] = f2bfu(oacc[g][nt][r]);
      }
    }
  }
}

// ---- merge NCH chunk partials + sink ----
template <int NCH, int QBLK, int NQT>
__global__ __launch_bounds__(256) void mergeN(
    const unsigned short* __restrict__ pO, const float* __restrict__ pm,
    const float* __restrict__ pl, const float* __restrict__ sinks,
    float* __restrict__ out) {
  const int t    = blockIdx.x * 256 + threadIdx.x;  // 262144 threads
  const int rid  = t >> 2;                          // h*2048 + qpos
  const int d0   = (t & 3) * 32;
  const int h    = rid >> 11;
  const int qpos = rid & 2047;
  const int qt   = qpos / QBLK;
  const int lr   = qpos % QBLK;
  const size_t base = ((size_t)(h * NQT + qt) * NCH) * QBLK + lr;
  const float sink = sinks[h];
  float mc[NCH], lc[NCH];
  float M = sink;
  #pragma unroll
  for (int c = 0; c < NCH; ++c) {
    mc[c] = pm[base + (size_t)c * QBLK];
    lc[c] = pl[base + (size_t)c * QBLK];
    M = fmaxf(M, mc[c]);
  }
  float denom = __expf(sink - M);
  float sc[NCH];
  #pragma unroll
  for (int c = 0; c < NCH; ++c) { sc[c] = __expf(mc[c] - M); denom += lc[c] * sc[c]; }
  const float inv = 1.0f / denom;
  float o[32];
  #pragma unroll
  for (int i = 0; i < 32; ++i) o[i] = 0.f;
  #pragma unroll
  for (int c = 0; c < NCH; ++c) {
    const unsigned short* pp = pO + (base + (size_t)c * QBLK) * 128 + d0;
    const float s = sc[c] * inv;
    #pragma unroll
    for (int i = 0; i < 4; ++i) {
      u16x8 a = *(const u16x8*)(pp + i * 8);
      #pragma unroll
      for (int jj = 0; jj < 8; ++jj) o[i*8+jj] += bfu2f(a[jj]) * s;
    }
  }
  float* op = out + (size_t)rid * 128 + d0;
  #pragma unroll
  for (int i = 0; i < 8; ++i)
    *(float4*)(op + i*4) = make_float4(o[i*4], o[i*4+1], o[i*4+2], o[i*4+3]);
}

extern "C" void kernel_launch(void* const* d_in, const int* in_sizes, int n_in,
                              void* d_out, int out_size, void* d_ws, size_t ws_size,
                              hipStream_t stream) {
  const float* q     = (const float*)d_in[0];
  const float* k     = (const float*)d_in[1];
  const float* v     = (const float*)d_in[2];
  const float* sinks = (const float*)d_in[3];
  const int*   bw    = (const int*)d_in[4];
  float* out = (float*)d_out;

  const size_t kvElems = (size_t)NKVH * SLEN * DDIM;
  unsigned short* kbf = (unsigned short*)d_ws;
  unsigned short* vtg = kbf + kvElems;
  unsigned short* pO  = vtg + kvElems;

  // NG=2 / NCH=4: partial rows = 32h * 16qt * 4c * 128 rows
  const size_t nPart4 = (size_t)NH * 16 * 4 * 128;
  const size_t need4  = 4 * kvElems + nPart4 * 128 * 2 + nPart4 * 8;  // ~86.0 MB
  // NG=1 / NCH=2: partial rows = 32h * 32qt * 2c * 64 rows
  const size_t nPart2 = (size_t)NH * 32 * 2 * 64;
  const size_t need2  = 4 * kvElems + nPart2 * 128 * 2 + nPart2 * 8;  // ~51.4 MB

  conv_kv<<<dim3(1024 + NKVH * 64 * 4), 256, 0, stream>>>(k, v, (unsigned*)kbf, vtg);

  if (ws_size >= need4) {
    float* pm = (float*)(pO + nPart4 * 128);
    float* pl = pm + nPart4;
    attn_fwd<2, 4><<<dim3(2048), 256, 0, stream>>>(q, kbf, vtg, sinks, bw, out, pO, pm, pl);
    mergeN<4, 128, 16><<<dim3(1024), 256, 0, stream>>>(pO, pm, pl, sinks, out);
  } else if (ws_size >= need2) {
    float* pm = (float*)(pO + nPart2 * 128);
    float* pl = pm + nPart2;
    attn_fwd<1, 2><<<dim3(2048), 256, 0, stream>>>(q, kbf, vtg, sinks, bw, out, pO, pm, pl);
    mergeN<2, 64, 32><<<dim3(1024), 256, 0, stream>>>(pO, pm, pl, sinks, out);
  } else {
    attn_fwd<1, 1><<<dim3(1024), 256, 0, stream>>>(q, kbf, vtg, sinks, bw, out, pO, nullptr, nullptr);
  }
}

// Round 10
// 85.829 us; speedup vs baseline: 1.2719x; 1.2719x over previous
//
#include <hip/hip_runtime.h>
#include <hip/hip_bf16.h>

typedef __bf16 bf16x8 __attribute__((ext_vector_type(8)));
typedef unsigned short u16x8 __attribute__((ext_vector_type(8)));
typedef unsigned int u32x4 __attribute__((ext_vector_type(4)));
typedef float f32x4 __attribute__((ext_vector_type(4)));

#define SLEN 2048
#define DDIM 128
#define NH   32
#define NKVH 8
#define KVB  32
#define MINIT  -1e30f
#define MASKED -3e30f

static __device__ __forceinline__ unsigned short f2bfu(float f) {
  union { float f; unsigned u; } x; x.f = f;
  return (unsigned short)((x.u + 0x7fffu + ((x.u >> 16) & 1u)) >> 16);
}
static __device__ __forceinline__ float bfu2f(unsigned short u) {
  union { unsigned u; float f; } x; x.u = ((unsigned)u) << 16;
  return x.f;
}
static __device__ __forceinline__ unsigned cvt_pk_bf16(float lo, float hi) {
  unsigned r;
  asm("v_cvt_pk_bf16_f32 %0, %1, %2" : "=v"(r) : "v"(lo), "v"(hi));
  return r;
}
static __device__ __forceinline__ f32x4 mfma_bf16(u16x8 a, u16x8 b, f32x4 c) {
  return __builtin_amdgcn_mfma_f32_16x16x32_bf16(
      __builtin_bit_cast(bf16x8, a), __builtin_bit_cast(bf16x8, b), c, 0, 0, 0);
}
static __device__ __forceinline__ void gload16(const unsigned short* g, unsigned short* l) {
  __builtin_amdgcn_global_load_lds(
      (const __attribute__((address_space(1))) unsigned*)g,
      (__attribute__((address_space(3))) unsigned*)l, 16, 0, 0);
}

// ---- fused prepass: K -> bf16 (blocks 0..1023), V -> bf16 transposed (1024..3071) ----
__global__ __launch_bounds__(256) void conv_kv(const float* __restrict__ k,
                                               const float* __restrict__ v,
                                               unsigned* __restrict__ kdst,
                                               unsigned short* __restrict__ vt) {
  __shared__ unsigned T32[32][17];
  const int bb = blockIdx.x;
  if (bb < 1024) {
    const int i = bb * 256 + threadIdx.x;
    const float4 f0 = ((const float4*)k)[2 * i];
    const float4 f1 = ((const float4*)k)[2 * i + 1];
    u32x4 o = { cvt_pk_bf16(f0.x, f0.y), cvt_pk_bf16(f0.z, f0.w),
                cvt_pk_bf16(f1.x, f1.y), cvt_pk_bf16(f1.z, f1.w) };
    ((u32x4*)kdst)[i] = o;
    return;
  }
  const int b   = bb - 1024;
  const int dt  = b & 3;
  const int st  = (b >> 2) & 63;
  const int kvh = b >> 8;
  const int r  = threadIdx.x >> 3;
  const int cg = threadIdx.x & 7;
  const float4 f = *(const float4*)(v + ((size_t)(kvh * SLEN + st * 32 + r) * DDIM) + dt * 32 + cg * 4);
  T32[r][cg * 2]     = cvt_pk_bf16(f.x, f.y);
  T32[r][cg * 2 + 1] = cvt_pk_bf16(f.z, f.w);
  __syncthreads();
  const int dr = threadIdx.x >> 3;
  const unsigned sel = (dr & 1) ? 0x07060302u : 0x05040100u;
  const unsigned a0 = T32[cg * 4 + 0][dr >> 1], a1 = T32[cg * 4 + 1][dr >> 1];
  const unsigned a2 = T32[cg * 4 + 2][dr >> 1], a3 = T32[cg * 4 + 3][dr >> 1];
  unsigned short* vp = vt + (size_t)kvh * DDIM * SLEN + (size_t)(dt * 32 + dr) * SLEN + st * 32 + cg * 4;
  const unsigned w0 = __builtin_amdgcn_perm(a1, a0, sel);
  const unsigned w1 = __builtin_amdgcn_perm(a3, a2, sel);
  vp[0] = (unsigned short)(w0 & 0xffff);
  vp[1] = (unsigned short)(w0 >> 16);
  vp[2] = (unsigned short)(w1 & 0xffff);
  vp[3] = (unsigned short)(w1 >> 16);
}

// ---- attention chunk kernel: swapped QK^T, in-reg softmax, gload_lds dbuf staging ----
template <int NCH>
__global__ __launch_bounds__(256, 4) void attn_fwd(
    const float* __restrict__ q, const unsigned short* __restrict__ kbf,
    const unsigned short* __restrict__ vtg, const float* __restrict__ sinks,
    const int* __restrict__ bwp, float* __restrict__ out,
    unsigned short* __restrict__ pO, float* __restrict__ pm,
    float* __restrict__ pl) {
  constexpr int NQT = 32;                  // 2048 / 64
  __shared__ unsigned short KB[2][KVB][DDIM];  // K tiles, slot-swizzled: slot^=(row&7)
  __shared__ unsigned short VB[2][DDIM][KVB];  // V^T tiles, slot-swizzled: slot^=((d>>1)&3)
  __shared__ unsigned Pex[4][16][16];          // P exchange, wave-private
  __shared__ float SmS[4][16];

  const int tid  = threadIdx.x;
  const int wid  = tid >> 6;
  const int lane = tid & 63;
  const int ln   = lane & 15;
  const int hi   = lane >> 4;

  const int B   = blockIdx.x;
  const int x   = B & 7;                   // XCD-resident kvh
  const int j   = B >> 3;
  constexpr int per = 4 * NCH;
  const int qt  = NQT - 1 - (j / per);     // descending: long chunks first
  const int rem = j % per;
  const int hh  = rem / NCH;
  const int c   = rem % NCH;
  const int h   = x * 4 + hh;
  const int kvh = x;
  const int q0  = qt * 64;
  const int qrow0 = q0 + wid * 16;
  const int qpos  = qrow0 + ln;            // lane's q-row

  const int bwv    = bwp[0];
  const int lo_off = (bwv > 0) ? (bwv - 1) : SLEN;

  const int T0 = max(0, q0 - lo_off) >> 5;
  const int T1 = (q0 + 63) >> 5;
  const int N  = T1 - T0 + 1;
  const int ch = (N + NCH - 1) / NCH;
  const int Ts = T0 + c * ch;
  const int Te = min(T1, Ts + ch - 1);

  const float sm_scale = 0.08838834764831845f;

  // ---- Q fragments (MFMA B-operand after swap) ----
  u16x8 qf[4];
  {
    const float* qp = q + ((size_t)(h * SLEN + qpos) * DDIM) + hi * 8;
    #pragma unroll
    for (int dk = 0; dk < 4; ++dk) {
      float4 f0 = *(const float4*)(qp + dk * 32);
      float4 f1 = *(const float4*)(qp + dk * 32 + 4);
      u32x4 t = { cvt_pk_bf16(f0.x, f0.y), cvt_pk_bf16(f0.z, f0.w),
                  cvt_pk_bf16(f1.x, f1.y), cvt_pk_bf16(f1.z, f1.w) };
      qf[dk] = __builtin_bit_cast(u16x8, t);
    }
  }

  float m_ln = MINIT, l_ln = 0.0f;
  f32x4 oacc[8];
  #pragma unroll
  for (int nt = 0; nt < 8; ++nt) oacc[nt] = f32x4{0.f, 0.f, 0.f, 0.f};

  const unsigned short* Kg = kbf + (size_t)kvh * SLEN * DDIM;
  const unsigned short* Vg = vtg + (size_t)kvh * DDIM * SLEN;

  // staging source offsets (elements); inverse-swizzled per-lane global address
  int koff[2], voff[2];
  #pragma unroll
  for (int c2 = 0; c2 < 2; ++c2) {
    const int r = wid * 8 + c2 * 4 + (lane >> 4);       // K row 0..31
    koff[c2] = r * DDIM + (((lane & 15) ^ (r & 7)) * 8);
    const int d = wid * 32 + c2 * 16 + (lane >> 2);     // V d-row 0..127
    voff[c2] = d * SLEN + (((lane & 3) ^ ((lane >> 3) & 3)) * 8);
  }

  // frag LDS element offsets (hoisted; swizzled reads)
  int kfo[4];
  #pragma unroll
  for (int dk = 0; dk < 4; ++dk)
    kfo[dk] = ln * DDIM + (((dk * 4 + hi) ^ (ln & 7)) * 8);
  const int vswz = (hi ^ ((ln >> 1) & 3)) * 8;

  if (Ts <= Te) {
    const int kbS = Ts * 32, kbE = Te * 32;

    // prologue: stage first tile into buf 0
    {
      gload16(Kg + (size_t)kbS * DDIM + koff[0], &KB[0][wid * 8][0]);
      gload16(Kg + (size_t)kbS * DDIM + koff[1], &KB[0][wid * 8 + 4][0]);
      gload16(Vg + (size_t)kbS + voff[0], &VB[0][wid * 32][0]);
      gload16(Vg + (size_t)kbS + voff[1], &VB[0][wid * 32 + 16][0]);
    }

    int cur = 0;
    for (int kb = kbS; kb <= kbE; kb += KVB) {
      __syncthreads();   // compiler drains vmcnt before barrier -> buf[cur] ready

      if (kb + KVB <= kbE) {   // issue next tile into other buffer (overlaps compute)
        const int nb = kb + KVB;
        const int nxt = cur ^ 1;
        gload16(Kg + (size_t)nb * DDIM + koff[0], &KB[nxt][wid * 8][0]);
        gload16(Kg + (size_t)nb * DDIM + koff[1], &KB[nxt][wid * 8 + 4][0]);
        gload16(Vg + (size_t)nb + voff[0], &VB[nxt][wid * 32][0]);
        gload16(Vg + (size_t)nb + voff[1], &VB[nxt][wid * 32 + 16][0]);
      }

      const bool skip = (kb > qrow0 + 15) || (kb + KVB - 1 < qrow0 - lo_off);
      if (!skip) {
        const unsigned short* kbp = &KB[cur][0][0];
        const unsigned short* vbp = &VB[cur][0][0];

        // ---- QK^T (swapped): S^T = mfma(K_frag, Q_frag) ----
        f32x4 sacc0 = {0,0,0,0}, sacc1 = {0,0,0,0};
        #pragma unroll
        for (int dk = 0; dk < 4; ++dk) {
          sacc0 = mfma_bf16(*(const u16x8*)(kbp + kfo[dk]), qf[dk], sacc0);
          sacc1 = mfma_bf16(*(const u16x8*)(kbp + kfo[dk] + 16 * DDIM), qf[dk], sacc1);
        }

        // ---- mask + scale ----
        float p[8];
        #pragma unroll
        for (int r = 0; r < 4; ++r) {
          const int kp0 = kb + hi * 4 + r;
          const int kp1 = kp0 + 16;
          p[r]     = ((kp0 <= qpos) && (kp0 >= qpos - lo_off)) ? sacc0[r] * sm_scale : MASKED;
          p[4 + r] = ((kp1 <= qpos) && (kp1 >= qpos - lo_off)) ? sacc1[r] * sm_scale : MASKED;
        }

        // ---- row max: 7 in-reg + 2 shfl ----
        float mx = fmaxf(fmaxf(fmaxf(p[0], p[1]), fmaxf(p[2], p[3])),
                         fmaxf(fmaxf(p[4], p[5]), fmaxf(p[6], p[7])));
        mx = fmaxf(mx, __shfl_xor(mx, 16));
        mx = fmaxf(mx, __shfl_xor(mx, 32));

        // ---- defer-max rescale (THR=8) ----
        if (__any(mx > m_ln + 8.0f)) {
          const float mn   = fmaxf(m_ln, mx);
          const float corr = __expf(m_ln - mn);
          l_ln *= corr;
          m_ln = mn;
          if (hi == 0) SmS[wid][ln] = corr;
          float c4[4];
          #pragma unroll
          for (int r = 0; r < 4; ++r) c4[r] = SmS[wid][hi * 4 + r];
          #pragma unroll
          for (int nt = 0; nt < 8; ++nt)
            #pragma unroll
            for (int r = 0; r < 4; ++r) oacc[nt][r] *= c4[r];
        }

        // ---- exp + row sum ----
        float s = 0.0f;
        #pragma unroll
        for (int jj = 0; jj < 8; ++jj) { p[jj] = __expf(p[jj] - m_ln); s += p[jj]; }
        s += __shfl_xor(s, 16);
        s += __shfl_xor(s, 32);
        l_ln += s;

        // ---- pack P and exchange to A-frag layout (wave-private, in-order) ----
        Pex[wid][ln][hi * 2]         = cvt_pk_bf16(p[0], p[1]);
        Pex[wid][ln][hi * 2 + 1]     = cvt_pk_bf16(p[2], p[3]);
        Pex[wid][ln][8 + hi * 2]     = cvt_pk_bf16(p[4], p[5]);
        Pex[wid][ln][8 + hi * 2 + 1] = cvt_pk_bf16(p[6], p[7]);
        const u16x8 pa = __builtin_bit_cast(u16x8, *(const u32x4*)&Pex[wid][ln][hi * 4]);

        // ---- PV ----
        #pragma unroll
        for (int nt = 0; nt < 8; ++nt) {
          const u16x8 vb = *(const u16x8*)(vbp + (nt * 16 + ln) * KVB + vswz);
          oacc[nt] = mfma_bf16(pa, vb, oacc[nt]);
        }
      }
      cur ^= 1;
    }
  }

  // ---- epilogue ----
  if (NCH == 1) {
    const float sink = sinks[h];
    const float M  = fmaxf(m_ln, sink);
    const float ed = __expf(m_ln - M);
    const float fac_ln = ed / (l_ln * ed + __expf(sink - M));
    if (hi == 0) SmS[wid][ln] = fac_ln;
    float fac4[4];
    #pragma unroll
    for (int r = 0; r < 4; ++r) fac4[r] = SmS[wid][hi * 4 + r];
    #pragma unroll
    for (int r = 0; r < 4; ++r) {
      float* op = out + ((size_t)(h * SLEN + qrow0 + hi*4 + r) * DDIM) + ln;
      #pragma unroll
      for (int nt = 0; nt < 8; ++nt) op[nt * 16] = oacc[nt][r] * fac4[r];
    }
  } else {
    const size_t Lb = ((size_t)(h * NQT + qt)) * NCH + c;
    if (hi == 0) {
      pm[Lb * 64 + wid * 16 + ln] = m_ln;
      pl[Lb * 64 + wid * 16 + ln] = l_ln;
    }
    #pragma unroll
    for (int r = 0; r < 4; ++r) {
      unsigned short* po = pO + (Lb * 64 + wid * 16 + hi * 4 + r) * 128 + ln;
      #pragma unroll
      for (int nt = 0; nt < 8; ++nt) po[nt * 16] = f2bfu(oacc[nt][r]);
    }
  }
}

// ---- merge NCH chunk partials + sink ----
template <int NCH, int QBLK, int NQT>
__global__ __launch_bounds__(256) void mergeN(
    const unsigned short* __restrict__ pO, const float* __restrict__ pm,
    const float* __restrict__ pl, const float* __restrict__ sinks,
    float* __restrict__ out) {
  const int t    = blockIdx.x * 256 + threadIdx.x;
  const int rid  = t >> 2;
  const int d0   = (t & 3) * 32;
  const int h    = rid >> 11;
  const int qpos = rid & 2047;
  const int qt   = qpos / QBLK;
  const int lr   = qpos % QBLK;
  const size_t base = ((size_t)(h * NQT + qt) * NCH) * QBLK + lr;
  const float sink = sinks[h];
  float mc[NCH], lc[NCH];
  float M = sink;
  #pragma unroll
  for (int c = 0; c < NCH; ++c) {
    mc[c] = pm[base + (size_t)c * QBLK];
    lc[c] = pl[base + (size_t)c * QBLK];
    M = fmaxf(M, mc[c]);
  }
  float denom = __expf(sink - M);
  float sc[NCH];
  #pragma unroll
  for (int c = 0; c < NCH; ++c) { sc[c] = __expf(mc[c] - M); denom += lc[c] * sc[c]; }
  const float inv = 1.0f / denom;
  float o[32];
  #pragma unroll
  for (int i = 0; i < 32; ++i) o[i] = 0.f;
  #pragma unroll
  for (int c = 0; c < NCH; ++c) {
    const unsigned short* pp = pO + (base + (size_t)c * QBLK) * 128 + d0;
    const float s = sc[c] * inv;
    #pragma unroll
    for (int i = 0; i < 4; ++i) {
      u16x8 a = *(const u16x8*)(pp + i * 8);
      #pragma unroll
      for (int jj = 0; jj < 8; ++jj) o[i*8+jj] += bfu2f(a[jj]) * s;
    }
  }
  float* op = out + (size_t)rid * 128 + d0;
  #pragma unroll
  for (int i = 0; i < 8; ++i)
    *(float4*)(op + i*4) = make_float4(o[i*4], o[i*4+1], o[i*4+2], o[i*4+3]);
}

extern "C" void kernel_launch(void* const* d_in, const int* in_sizes, int n_in,
                              void* d_out, int out_size, void* d_ws, size_t ws_size,
                              hipStream_t stream) {
  const float* q     = (const float*)d_in[0];
  const float* k     = (const float*)d_in[1];
  const float* v     = (const float*)d_in[2];
  const float* sinks = (const float*)d_in[3];
  const int*   bw    = (const int*)d_in[4];
  float* out = (float*)d_out;

  const size_t kvElems = (size_t)NKVH * SLEN * DDIM;
  unsigned short* kbf = (unsigned short*)d_ws;
  unsigned short* vtg = kbf + kvElems;
  unsigned short* pO  = vtg + kvElems;

  // NCH=2: partial rows = 32h * 32qt * 2c * 64 rows
  const size_t nPart2 = (size_t)NH * 32 * 2 * 64;
  const size_t need2  = 4 * kvElems + nPart2 * 128 * 2 + nPart2 * 8;  // ~51.4 MB

  conv_kv<<<dim3(1024 + NKVH * 64 * 4), 256, 0, stream>>>(k, v, (unsigned*)kbf, vtg);

  if (ws_size >= need2) {
    float* pm = (float*)(pO + nPart2 * 128);
    float* pl = pm + nPart2;
    attn_fwd<2><<<dim3(2048), 256, 0, stream>>>(q, kbf, vtg, sinks, bw, out, pO, pm, pl);
    mergeN<2, 64, 32><<<dim3(1024), 256, 0, stream>>>(pO, pm, pl, sinks, out);
  } else {
    attn_fwd<1><<<dim3(1024), 256, 0, stream>>>(q, kbf, vtg, sinks, bw, out, pO, nullptr, nullptr);
  }
}

// Round 11
// 75.269 us; speedup vs baseline: 1.4503x; 1.1403x over previous
//
#include <hip/hip_runtime.h>
#include <hip/hip_bf16.h>

typedef __bf16 bf16x8 __attribute__((ext_vector_type(8)));
typedef unsigned short u16x8 __attribute__((ext_vector_type(8)));
typedef unsigned int u32x4 __attribute__((ext_vector_type(4)));
typedef float f32x4 __attribute__((ext_vector_type(4)));

#define SLEN 2048
#define DDIM 128
#define NH   32
#define NKVH 8
#define KVB  32
#define MINIT  -1e30f
#define MASKED -3e30f

static __device__ __forceinline__ unsigned short f2bfu(float f) {
  union { float f; unsigned u; } x; x.f = f;
  return (unsigned short)((x.u + 0x7fffu + ((x.u >> 16) & 1u)) >> 16);
}
static __device__ __forceinline__ float bfu2f(unsigned short u) {
  union { unsigned u; float f; } x; x.u = ((unsigned)u) << 16;
  return x.f;
}
static __device__ __forceinline__ unsigned cvt_pk_bf16(float lo, float hi) {
  unsigned r;
  asm("v_cvt_pk_bf16_f32 %0, %1, %2" : "=v"(r) : "v"(lo), "v"(hi));
  return r;
}
static __device__ __forceinline__ f32x4 mfma_bf16(u16x8 a, u16x8 b, f32x4 c) {
  return __builtin_amdgcn_mfma_f32_16x16x32_bf16(
      __builtin_bit_cast(bf16x8, a), __builtin_bit_cast(bf16x8, b), c, 0, 0, 0);
}
// XOR value spreading K rows {r, r+8, r+16, r+24} across slots
static __device__ __forceinline__ int vswz_k(int row) {
  return (row & 3) | (((row >> 3) & 1) << 2);
}

// ---- fused prepass: K -> bf16 (blocks 0..1023), V -> bf16 transposed (1024..3071) ----
__global__ __launch_bounds__(256) void conv_kv(const float* __restrict__ k,
                                               const float* __restrict__ v,
                                               unsigned* __restrict__ kdst,
                                               unsigned short* __restrict__ vt) {
  __shared__ unsigned T32[32][17];
  const int bb = blockIdx.x;
  if (bb < 1024) {
    const int i = bb * 256 + threadIdx.x;
    const float4 f0 = ((const float4*)k)[2 * i];
    const float4 f1 = ((const float4*)k)[2 * i + 1];
    u32x4 o = { cvt_pk_bf16(f0.x, f0.y), cvt_pk_bf16(f0.z, f0.w),
                cvt_pk_bf16(f1.x, f1.y), cvt_pk_bf16(f1.z, f1.w) };
    ((u32x4*)kdst)[i] = o;
    return;
  }
  const int b   = bb - 1024;
  const int dt  = b & 3;
  const int st  = (b >> 2) & 63;
  const int kvh = b >> 8;
  const int r  = threadIdx.x >> 3;
  const int cg = threadIdx.x & 7;
  const float4 f = *(const float4*)(v + ((size_t)(kvh * SLEN + st * 32 + r) * DDIM) + dt * 32 + cg * 4);
  T32[r][cg * 2]     = cvt_pk_bf16(f.x, f.y);
  T32[r][cg * 2 + 1] = cvt_pk_bf16(f.z, f.w);
  __syncthreads();
  const int dr = threadIdx.x >> 3;
  const unsigned sel = (dr & 1) ? 0x07060302u : 0x05040100u;
  const unsigned a0 = T32[cg * 4 + 0][dr >> 1], a1 = T32[cg * 4 + 1][dr >> 1];
  const unsigned a2 = T32[cg * 4 + 2][dr >> 1], a3 = T32[cg * 4 + 3][dr >> 1];
  unsigned short* vp = vt + (size_t)kvh * DDIM * SLEN + (size_t)(dt * 32 + dr) * SLEN + st * 32 + cg * 4;
  const unsigned w0 = __builtin_amdgcn_perm(a1, a0, sel);
  const unsigned w1 = __builtin_amdgcn_perm(a3, a2, sel);
  vp[0] = (unsigned short)(w0 & 0xffff);
  vp[1] = (unsigned short)(w0 >> 16);
  vp[2] = (unsigned short)(w1 & 0xffff);
  vp[3] = (unsigned short)(w1 >> 16);
}

// ---- attention chunk kernel: swapped QK^T + K-row perm -> P stays in registers ----
template <int NCH>
__global__ __launch_bounds__(256, 4) void attn_fwd(
    const float* __restrict__ q, const unsigned short* __restrict__ kbf,
    const unsigned short* __restrict__ vtg, const float* __restrict__ sinks,
    const int* __restrict__ bwp, float* __restrict__ out,
    unsigned short* __restrict__ pO, float* __restrict__ pm,
    float* __restrict__ pl) {
  constexpr int NQT = 32;                 // 2048 / 64
  __shared__ unsigned short Kl[KVB * DDIM];   // unpadded, slot-swizzled
  __shared__ unsigned short Vt[DDIM * KVB];   // unpadded, slot-swizzled
  __shared__ float SmS[4][16];

  const int tid  = threadIdx.x;
  const int wid  = tid >> 6;
  const int lane = tid & 63;
  const int ln   = lane & 15;
  const int hi   = lane >> 4;

  const int B   = blockIdx.x;
  const int x   = B & 7;                  // XCD-resident kvh
  const int j   = B >> 3;
  constexpr int per = 4 * NCH;
  const int qt  = NQT - 1 - (j / per);    // descending: long chunks first
  const int rem = j % per;
  const int hh  = rem / NCH;
  const int c   = rem % NCH;
  const int h   = x * 4 + hh;
  const int kvh = x;
  const int q0  = qt * 64;
  const int qrow0 = q0 + wid * 16;
  const int qpos  = qrow0 + ln;           // lane's q-row

  const int bwv    = bwp[0];
  const int lo_off = (bwv > 0) ? (bwv - 1) : SLEN;

  const int T0 = max(0, q0 - lo_off) >> 5;
  const int T1 = (q0 + 63) >> 5;
  const int N  = T1 - T0 + 1;
  const int ch = (N + NCH - 1) / NCH;
  const int Ts = T0 + c * ch;
  const int Te = min(T1, Ts + ch - 1);

  const float sm_scale = 0.08838834764831845f;

  // ---- Q fragments (MFMA B-operand after swap) ----
  u16x8 qf[4];
  {
    const float* qp = q + ((size_t)(h * SLEN + qpos) * DDIM) + hi * 8;
    #pragma unroll
    for (int dk = 0; dk < 4; ++dk) {
      float4 f0 = *(const float4*)(qp + dk * 32);
      float4 f1 = *(const float4*)(qp + dk * 32 + 4);
      u32x4 t = { cvt_pk_bf16(f0.x, f0.y), cvt_pk_bf16(f0.z, f0.w),
                  cvt_pk_bf16(f1.x, f1.y), cvt_pk_bf16(f1.z, f1.w) };
      qf[dk] = __builtin_bit_cast(u16x8, t);
    }
  }

  float m_ln = MINIT, l_ln = 0.0f;
  f32x4 oacc[8];
  #pragma unroll
  for (int nt = 0; nt < 8; ++nt) oacc[nt] = f32x4{0.f, 0.f, 0.f, 0.f};

  const unsigned short* Kg = kbf + (size_t)kvh * SLEN * DDIM;
  const unsigned short* Vg = vtg + (size_t)kvh * DDIM * SLEN;

  // ---- staging coords: global linear, LDS swizzled ----
  const int kr0 = tid >> 4, sk = tid & 15;           // K rows 0-15 / 16-31
  const int kr1 = kr0 + 16;
  const int kw0 = kr0 * DDIM + (((sk & 8) | ((sk & 7) ^ vswz_k(kr0))) * 8);
  const int kw1 = kr1 * DDIM + (((sk & 8) | ((sk & 7) ^ vswz_k(kr1))) * 8);
  const int vr0 = tid >> 2, sv = tid & 3;            // V d-rows 0-63 / 64-127
  const int vr1 = vr0 + 64;
  const int vw0 = vr0 * KVB + ((sv ^ ((vr0 >> 1) & 3)) * 8);
  const int vw1 = vr1 * KVB + ((sv ^ ((vr1 >> 1) & 3)) * 8);

  // ---- read offsets: K rows permuted so lane holds k = hi*8+0..7 ----
  const int prow = ((ln >> 2) << 3) | (ln & 3);      // perm(ln)
  const int vk   = (ln & 3) | (((ln >> 2) & 1) << 2);
  int kfo[4];
  #pragma unroll
  for (int dk = 0; dk < 4; ++dk) {
    const int s = dk * 4 + hi;
    kfo[dk] = prow * DDIM + (((s & 8) | ((s & 7) ^ vk)) * 8);
  }
  const int vro = ln * KVB + ((hi ^ ((ln >> 1) & 3)) * 8);  // + nt*16*KVB

  if (Ts <= Te) {
    const int kbS = Ts * 32, kbE = Te * 32;

    u16x8 pk0, pk1, pv0, pv1;
    {
      pk0 = *(const u16x8*)(Kg + (size_t)(kbS + kr0) * DDIM + sk * 8);
      pk1 = *(const u16x8*)(Kg + (size_t)(kbS + kr1) * DDIM + sk * 8);
      pv0 = *(const u16x8*)(Vg + (size_t)vr0 * SLEN + kbS + sv * 8);
      pv1 = *(const u16x8*)(Vg + (size_t)vr1 * SLEN + kbS + sv * 8);
    }

    for (int kb = kbS; kb <= kbE; kb += KVB) {
      __syncthreads();
      *(u16x8*)&Kl[kw0] = pk0;
      *(u16x8*)&Kl[kw1] = pk1;
      *(u16x8*)&Vt[vw0] = pv0;
      *(u16x8*)&Vt[vw1] = pv1;
      __syncthreads();

      {
        const int nb = min(kb + KVB, kbE);
        pk0 = *(const u16x8*)(Kg + (size_t)(nb + kr0) * DDIM + sk * 8);
        pk1 = *(const u16x8*)(Kg + (size_t)(nb + kr1) * DDIM + sk * 8);
        pv0 = *(const u16x8*)(Vg + (size_t)vr0 * SLEN + nb + sv * 8);
        pv1 = *(const u16x8*)(Vg + (size_t)vr1 * SLEN + nb + sv * 8);
      }

      if (kb > qrow0 + 15) continue;
      if (kb + KVB - 1 < qrow0 - lo_off) continue;

      // ---- QK^T (swapped, K rows permuted): lane gets k = hi*8 + 0..7 ----
      f32x4 sacc0 = {0,0,0,0}, sacc1 = {0,0,0,0};
      #pragma unroll
      for (int dk = 0; dk < 4; ++dk) {
        sacc0 = mfma_bf16(*(const u16x8*)&Kl[kfo[dk]], qf[dk], sacc0);           // rows perm
        sacc1 = mfma_bf16(*(const u16x8*)&Kl[kfo[dk] + 4 * DDIM], qf[dk], sacc1); // rows perm+4
      }

      // ---- mask + scale (k-local = hi*8 + j) ----
      float p[8];
      #pragma unroll
      for (int r = 0; r < 4; ++r) {
        const int kp0 = kb + hi * 8 + r;
        const int kp1 = kp0 + 4;
        p[r]     = ((kp0 <= qpos) && (kp0 >= qpos - lo_off)) ? sacc0[r] * sm_scale : MASKED;
        p[4 + r] = ((kp1 <= qpos) && (kp1 >= qpos - lo_off)) ? sacc1[r] * sm_scale : MASKED;
      }

      // ---- row max: 7 in-reg + 2 shfl ----
      float mx = fmaxf(fmaxf(fmaxf(p[0], p[1]), fmaxf(p[2], p[3])),
                       fmaxf(fmaxf(p[4], p[5]), fmaxf(p[6], p[7])));
      mx = fmaxf(mx, __shfl_xor(mx, 16));
      mx = fmaxf(mx, __shfl_xor(mx, 32));

      // ---- defer-max rescale (THR=8) ----
      if (__any(mx > m_ln + 8.0f)) {
        const float mn   = fmaxf(m_ln, mx);
        const float corr = __expf(m_ln - mn);
        l_ln *= corr;
        m_ln = mn;
        if (hi == 0) SmS[wid][ln] = corr;
        float c4[4];
        #pragma unroll
        for (int r = 0; r < 4; ++r) c4[r] = SmS[wid][hi * 4 + r];
        #pragma unroll
        for (int nt = 0; nt < 8; ++nt)
          #pragma unroll
          for (int r = 0; r < 4; ++r) oacc[nt][r] *= c4[r];
      }

      // ---- exp + row sum ----
      float s = 0.0f;
      #pragma unroll
      for (int jj = 0; jj < 8; ++jj) { p[jj] = __expf(p[jj] - m_ln); s += p[jj]; }
      s += __shfl_xor(s, 16);
      s += __shfl_xor(s, 32);
      l_ln += s;

      // ---- P -> bf16 A-frag, entirely in registers (k order: hi*8+0..7) ----
      // sacc0 r -> k=hi*8+r (j=0..3), sacc1 r -> k=hi*8+4+r (j=4..7)
      const u32x4 paw = { cvt_pk_bf16(p[0], p[1]), cvt_pk_bf16(p[2], p[3]),
                          cvt_pk_bf16(p[4], p[5]), cvt_pk_bf16(p[6], p[7]) };
      const u16x8 pa = __builtin_bit_cast(u16x8, paw);

      // ---- PV ----
      #pragma unroll
      for (int nt = 0; nt < 8; ++nt) {
        const u16x8 vb = *(const u16x8*)&Vt[vro + nt * 16 * KVB];
        oacc[nt] = mfma_bf16(pa, vb, oacc[nt]);
      }
    }
  }

  // ---- epilogue ----
  if (NCH == 1) {
    const float sink = sinks[h];
    const float M  = fmaxf(m_ln, sink);
    const float ed = __expf(m_ln - M);
    const float fac_ln = ed / (l_ln * ed + __expf(sink - M));
    if (hi == 0) SmS[wid][ln] = fac_ln;
    float fac4[4];
    #pragma unroll
    for (int r = 0; r < 4; ++r) fac4[r] = SmS[wid][hi * 4 + r];
    #pragma unroll
    for (int r = 0; r < 4; ++r) {
      float* op = out + ((size_t)(h * SLEN + qrow0 + hi*4 + r) * DDIM) + ln;
      #pragma unroll
      for (int nt = 0; nt < 8; ++nt) op[nt * 16] = oacc[nt][r] * fac4[r];
    }
  } else {
    const size_t Lb = ((size_t)(h * NQT + qt)) * NCH + c;
    if (hi == 0) {
      pm[Lb * 64 + wid * 16 + ln] = m_ln;
      pl[Lb * 64 + wid * 16 + ln] = l_ln;
    }
    #pragma unroll
    for (int r = 0; r < 4; ++r) {
      unsigned short* po = pO + (Lb * 64 + wid * 16 + hi * 4 + r) * 128 + ln;
      #pragma unroll
      for (int nt = 0; nt < 8; ++nt) po[nt * 16] = f2bfu(oacc[nt][r]);
    }
  }
}

// ---- merge NCH chunk partials + sink ----
template <int NCH, int QBLK, int NQT>
__global__ __launch_bounds__(256) void mergeN(
    const unsigned short* __restrict__ pO, const float* __restrict__ pm,
    const float* __restrict__ pl, const float* __restrict__ sinks,
    float* __restrict__ out) {
  const int t    = blockIdx.x * 256 + threadIdx.x;
  const int rid  = t >> 2;
  const int d0   = (t & 3) * 32;
  const int h    = rid >> 11;
  const int qpos = rid & 2047;
  const int qt   = qpos / QBLK;
  const int lr   = qpos % QBLK;
  const size_t base = ((size_t)(h * NQT + qt) * NCH) * QBLK + lr;
  const float sink = sinks[h];
  float mc[NCH], lc[NCH];
  float M = sink;
  #pragma unroll
  for (int c = 0; c < NCH; ++c) {
    mc[c] = pm[base + (size_t)c * QBLK];
    lc[c] = pl[base + (size_t)c * QBLK];
    M = fmaxf(M, mc[c]);
  }
  float denom = __expf(sink - M);
  float sc[NCH];
  #pragma unroll
  for (int c = 0; c < NCH; ++c) { sc[c] = __expf(mc[c] - M); denom += lc[c] * sc[c]; }
  const float inv = 1.0f / denom;
  float o[32];
  #pragma unroll
  for (int i = 0; i < 32; ++i) o[i] = 0.f;
  #pragma unroll
  for (int c = 0; c < NCH; ++c) {
    const unsigned short* pp = pO + (base + (size_t)c * QBLK) * 128 + d0;
    const float s = sc[c] * inv;
    #pragma unroll
    for (int i = 0; i < 4; ++i) {
      u16x8 a = *(const u16x8*)(pp + i * 8);
      #pragma unroll
      for (int jj = 0; jj < 8; ++jj) o[i*8+jj] += bfu2f(a[jj]) * s;
    }
  }
  float* op = out + (size_t)rid * 128 + d0;
  #pragma unroll
  for (int i = 0; i < 8; ++i)
    *(float4*)(op + i*4) = make_float4(o[i*4], o[i*4+1], o[i*4+2], o[i*4+3]);
}

extern "C" void kernel_launch(void* const* d_in, const int* in_sizes, int n_in,
                              void* d_out, int out_size, void* d_ws, size_t ws_size,
                              hipStream_t stream) {
  const float* q     = (const float*)d_in[0];
  const float* k     = (const float*)d_in[1];
  const float* v     = (const float*)d_in[2];
  const float* sinks = (const float*)d_in[3];
  const int*   bw    = (const int*)d_in[4];
  float* out = (float*)d_out;

  const size_t kvElems = (size_t)NKVH * SLEN * DDIM;
  unsigned short* kbf = (unsigned short*)d_ws;
  unsigned short* vtg = kbf + kvElems;
  unsigned short* pO  = vtg + kvElems;

  // NCH=2: partial rows = 32h * 32qt * 2c * 64 rows
  const size_t nPart2 = (size_t)NH * 32 * 2 * 64;
  const size_t need2  = 4 * kvElems + nPart2 * 128 * 2 + nPart2 * 8;  // ~51.4 MB

  conv_kv<<<dim3(1024 + NKVH * 64 * 4), 256, 0, stream>>>(k, v, (unsigned*)kbf, vtg);

  if (ws_size >= need2) {
    float* pm = (float*)(pO + nPart2 * 128);
    float* pl = pm + nPart2;
    attn_fwd<2><<<dim3(2048), 256, 0, stream>>>(q, kbf, vtg, sinks, bw, out, pO, pm, pl);
    mergeN<2, 64, 32><<<dim3(1024), 256, 0, stream>>>(pO, pm, pl, sinks, out);
  } else {
    attn_fwd<1><<<dim3(1024), 256, 0, stream>>>(q, kbf, vtg, sinks, bw, out, pO, nullptr, nullptr);
  }
}